// Round 5
// baseline (207.176 us; speedup 1.0000x reference)
//
#include <hip/hip_runtime.h>
#include <stdint.h>

typedef __attribute__((ext_vector_type(4))) int i32x4;

#define N_FRAMES 16386
#define D_DIM    1024
#define O_DIM    2048
#define L_CTX    3
#define K_DIM    3072   // D_DIM * L_CTX
#define T_DIM    16384  // N_FRAMES - L_CTX + 1
#define NKT      24     // K_DIM / 128  (128-byte K-tiles)

// workspace byte offsets
#define WS_MM     0u
#define WS_PARAMS 64u
#define WS_CO     256u
#define WS_S      16384u
#define WS_CT     98304u
#define WS_QW     262144u
#define WS_QX     8388608u

struct Params {
  float w_scale, in_scale, cscale;
  int   w_zp, in_zp, konst;
};

typedef __attribute__((address_space(3))) void       lds_void;
typedef const __attribute__((address_space(1))) void gbl_void;

__device__ __forceinline__ unsigned flip_f(float f) {
  unsigned u = __float_as_uint(f);
  return (u & 0x80000000u) ? ~u : (u | 0x80000000u);
}
__device__ __forceinline__ float unflip_f(unsigned v) {
  unsigned u = (v & 0x80000000u) ? (v ^ 0x80000000u) : ~v;
  return __uint_as_float(u);
}

__global__ void init_kernel(unsigned* mm) {
  mm[0] = 0xFFFFFFFFu;
  mm[1] = 0u;
}

__global__ __launch_bounds__(256) void wminmax_kernel(const float4* __restrict__ w,
                                                      unsigned* mm, int n4) {
  unsigned lmin = 0xFFFFFFFFu, lmax = 0u;
  for (int i = blockIdx.x * blockDim.x + threadIdx.x; i < n4; i += gridDim.x * blockDim.x) {
    float4 v = w[i];
    unsigned a = flip_f(v.x), b = flip_f(v.y), c = flip_f(v.z), d = flip_f(v.w);
    lmin = min(lmin, min(min(a, b), min(c, d)));
    lmax = max(lmax, max(max(a, b), max(c, d)));
  }
#pragma unroll
  for (int off = 32; off > 0; off >>= 1) {
    lmin = min(lmin, (unsigned)__shfl_xor((int)lmin, off, 64));
    lmax = max(lmax, (unsigned)__shfl_xor((int)lmax, off, 64));
  }
  if ((threadIdx.x & 63) == 0) {
    atomicMin(&mm[0], lmin);
    atomicMax(&mm[1], lmax);
  }
}

__global__ void params_kernel(const unsigned* __restrict__ mm,
                              const float* __restrict__ in_min,
                              const float* __restrict__ in_max,
                              Params* __restrict__ p) {
  float wmin = unflip_f(mm[0]);
  float wmax = unflip_f(mm[1]);
  float ws = (wmax - wmin) / 254.0f;
  float wz = -127.0f - wmin / ws;
  wz = fminf(fmaxf(wz, -127.0f), 127.0f);
  int wzp = (int)wz;
  float imin = *in_min, imax = *in_max;
  float is = (imax - imin) / 254.0f;
  float iz = -127.0f - imin / is;
  iz = fminf(fmaxf(iz, -127.0f), 127.0f);
  int izp = (int)iz;
  p->w_scale = ws; p->in_scale = is; p->cscale = is * ws;
  p->w_zp = wzp;   p->in_zp = izp;
  p->konst = K_DIM * wzp * izp;
}

__global__ __launch_bounds__(256) void quantw_kernel(
    const float* __restrict__ w, const float* __restrict__ bias,
    const Params* __restrict__ p, int8_t* __restrict__ qw,
    int* __restrict__ co, float* __restrict__ dq, float* __restrict__ bias_out) {
  const int o = blockIdx.x;
  const float ws = p->w_scale;
  const float zpf = (float)p->w_zp;
  const float* wrow = w + (size_t)o * K_DIM;
  float* dqrow = dq + (size_t)o * K_DIM;
  int8_t* qrow = qw + (size_t)o * K_DIM;
  int sum = 0;
#pragma unroll
  for (int pass = 0; pass < 3; ++pass) {
    const int k = (pass << 10) + (threadIdx.x << 2);
    float4 v = *(const float4*)(wrow + k);
    int8_t c0 = (int8_t)(int)rintf(v.x / ws + zpf);
    int8_t c1 = (int8_t)(int)rintf(v.y / ws + zpf);
    int8_t c2 = (int8_t)(int)rintf(v.z / ws + zpf);
    int8_t c3 = (int8_t)(int)rintf(v.w / ws + zpf);
    sum += (int)c0 + (int)c1 + (int)c2 + (int)c3;
    unsigned packed = (unsigned)(uint8_t)c0 | ((unsigned)(uint8_t)c1 << 8)
                    | ((unsigned)(uint8_t)c2 << 16) | ((unsigned)(uint8_t)c3 << 24);
    *(unsigned*)(qrow + k) = packed;
    float4 d;
    d.x = ((float)c0 - zpf) * ws;
    d.y = ((float)c1 - zpf) * ws;
    d.z = ((float)c2 - zpf) * ws;
    d.w = ((float)c3 - zpf) * ws;
    *(float4*)(dqrow + k) = d;
  }
  __shared__ int red[4];
#pragma unroll
  for (int off = 32; off > 0; off >>= 1) sum += __shfl_xor(sum, off, 64);
  if ((threadIdx.x & 63) == 0) red[threadIdx.x >> 6] = sum;
  __syncthreads();
  if (threadIdx.x == 0) {
    int tot = red[0] + red[1] + red[2] + red[3];
    co[o] = -p->in_zp * tot;
    bias_out[o] = bias[o];
  }
}

__global__ __launch_bounds__(256) void quantx_kernel(
    const float* __restrict__ x, const Params* __restrict__ p,
    int8_t* __restrict__ qx, int* __restrict__ s) {
  const int n = blockIdx.x;
  const float is = p->in_scale;
  const float zpf = (float)p->in_zp;
  const float4 v = *((const float4*)(x + (size_t)n * D_DIM) + threadIdx.x);
  int8_t c0 = (int8_t)(int)rintf(v.x / is + zpf);
  int8_t c1 = (int8_t)(int)rintf(v.y / is + zpf);
  int8_t c2 = (int8_t)(int)rintf(v.z / is + zpf);
  int8_t c3 = (int8_t)(int)rintf(v.w / is + zpf);
  unsigned packed = (unsigned)(uint8_t)c0 | ((unsigned)(uint8_t)c1 << 8)
                  | ((unsigned)(uint8_t)c2 << 16) | ((unsigned)(uint8_t)c3 << 24);
  ((unsigned*)(qx + (size_t)n * D_DIM))[threadIdx.x] = packed;
  int sum = (int)c0 + (int)c1 + (int)c2 + (int)c3;
  __shared__ int red[4];
#pragma unroll
  for (int off = 32; off > 0; off >>= 1) sum += __shfl_xor(sum, off, 64);
  if ((threadIdx.x & 63) == 0) red[threadIdx.x >> 6] = sum;
  __syncthreads();
  if (threadIdx.x == 0) s[n] = red[0] + red[1] + red[2] + red[3];
}

__global__ __launch_bounds__(256) void ct_kernel(const int* __restrict__ s,
                                                 const Params* __restrict__ p,
                                                 int* __restrict__ ct) {
  const int t = blockIdx.x * blockDim.x + threadIdx.x;
  if (t < T_DIM) ct[t] = p->konst - p->w_zp * (s[t] + s[t + 1] + s[t + 2]);
}

// int8 NT GEMM, 256x256 tile, 128B K-tiles, 8 waves, m201-style 4-phase/K-tile:
// each phase {4-8 ds_read (for later phase) | 0-4 stage gloads | bar |
// counted lgkm | setprio | 16 MFMA (one C-quadrant) | setprio | [vmcnt(2)] | bar}.
__global__ __launch_bounds__(512, 2) void gemm_kernel(
    const int8_t* __restrict__ qx, const int8_t* __restrict__ qw,
    const int* __restrict__ co, const int* __restrict__ ct,
    const float* __restrict__ bias, const Params* __restrict__ p,
    float* __restrict__ out) {
  __shared__ int8_t A_lds[2][256 * 128];   // 32 KB per buf
  __shared__ int8_t B_lds[2][256 * 128];

  const int bid = blockIdx.x;
  const int tn = bid & 7;   // all blocks with tn=j land on XCD j: B panel L2-resident
  const int tm = bid >> 3;
  const int m0 = tm << 8, n0 = tn << 8;
  const int tid = threadIdx.x;
  const int lane = tid & 63, wave = tid >> 6;
  const int wm = wave >> 2, wn = wave & 3;   // 2x4 wave grid, per-wave 128x64
  const int lr = lane & 15, kg = lane >> 4;
  const int lr7 = lane & 7;

  // staging: thread t covers row t>>3, lds chunk t&7; source chunk pre-swizzled
  // with ^(row&7) so linear LDS dest holds swizzled layout.
  const int st_row = tid >> 3;
  const int st_sc  = ((tid & 7) ^ (st_row & 7)) << 4;
  const int8_t* qxa = qx + (size_t)(m0 + st_row) * D_DIM + st_sc;
  const int8_t* qwb = qw + (size_t)(n0 + st_row) * K_DIM + st_sc;

  // fragment read: phys chunk = ((ks<<2)|kg) ^ (row&7); row&7 == lr7
  const int c0 = (kg ^ lr7) << 4;            // ks=0; ks=1 -> c0 ^ 64
  const int arow = ((wm << 7) + lr) << 7;    // A row base byte
  const int brow = ((wn << 6) + lr) << 7;

  i32x4 aLo[4][2], aHi[4][2], bLo[2][2], bHi[2][2];
  i32x4 acc[8][4] = {};

  // stage one 128-row half (h=0/1) of A or B for tile kt into LDS[buf]: 2 gloads
  auto stageA_h = [&](int buf, int kt, int h) {
#pragma unroll
    for (int j = 0; j < 2; ++j) {
      const int jj = (h << 1) + j;
      __builtin_amdgcn_global_load_lds(
          (gbl_void*)(qxa + (kt << 7) + (size_t)(jj << 6) * D_DIM),
          (lds_void*)(&A_lds[buf][(jj << 13) + (wave << 10)]), 16, 0, 0);
    }
  };
  auto stageB_h = [&](int buf, int kt, int h) {
#pragma unroll
    for (int j = 0; j < 2; ++j) {
      const int jj = (h << 1) + j;
      __builtin_amdgcn_global_load_lds(
          (gbl_void*)(qwb + (kt << 7) + (size_t)(jj << 6) * K_DIM),
          (lds_void*)(&B_lds[buf][(jj << 13) + (wave << 10)]), 16, 0, 0);
    }
  };
  auto readALo = [&](int bf) {
#pragma unroll
    for (int m = 0; m < 4; ++m)
#pragma unroll
      for (int ks = 0; ks < 2; ++ks)
        aLo[m][ks] = *(const i32x4*)&A_lds[bf][arow + (m << 11) + (c0 ^ (ks << 6))];
  };
  auto readAHi = [&](int bf) {
#pragma unroll
    for (int m = 0; m < 4; ++m)
#pragma unroll
      for (int ks = 0; ks < 2; ++ks)
        aHi[m][ks] = *(const i32x4*)&A_lds[bf][arow + ((m + 4) << 11) + (c0 ^ (ks << 6))];
  };
  auto readBLo = [&](int bf) {
#pragma unroll
    for (int n = 0; n < 2; ++n)
#pragma unroll
      for (int ks = 0; ks < 2; ++ks)
        bLo[n][ks] = *(const i32x4*)&B_lds[bf][brow + (n << 11) + (c0 ^ (ks << 6))];
  };
  auto readBHi = [&](int bf) {
#pragma unroll
    for (int n = 0; n < 2; ++n)
#pragma unroll
      for (int ks = 0; ks < 2; ++ks)
        bHi[n][ks] = *(const i32x4*)&B_lds[bf][brow + ((n + 2) << 11) + (c0 ^ (ks << 6))];
  };

  // prologue: stage tiles 0,1 fully; wait tile 0 (tile 1's 8 stay in flight);
  // read aLo/bLo of tile 0.
  stageA_h(0, 0, 0); stageA_h(0, 0, 1); stageB_h(0, 0, 0); stageB_h(0, 0, 1);
  stageA_h(1, 1, 0); stageA_h(1, 1, 1); stageB_h(1, 1, 0); stageB_h(1, 1, 1);
  asm volatile("s_waitcnt vmcnt(8)" ::: "memory");
  __builtin_amdgcn_s_barrier();
  readALo(0);
  readBLo(0);

  for (int kt = 0; kt < NKT; ++kt) {
    const int buf = kt & 1, nxt = buf ^ 1;
    const bool rd_nxt = (kt + 1 < NKT);
    const bool st_nxt = (kt + 2 < NKT);

    // ---- P0: read bHi(kt); MFMA Q00 = aLo x bLo ----
    readBHi(buf);
    __builtin_amdgcn_s_barrier();
    asm volatile("s_waitcnt lgkmcnt(4)" ::: "memory");
    __builtin_amdgcn_s_setprio(1);
#pragma unroll
    for (int m = 0; m < 4; ++m)
#pragma unroll
      for (int n = 0; n < 2; ++n)
#pragma unroll
        for (int ks = 0; ks < 2; ++ks)
          acc[m][n] = __builtin_amdgcn_mfma_i32_16x16x64_i8(aLo[m][ks], bLo[n][ks], acc[m][n], 0, 0, 0);
    __builtin_amdgcn_s_setprio(0);
    __builtin_amdgcn_s_barrier();

    // ---- P1: read aHi(kt); stage Bh0(kt+2); MFMA Q01 = aLo x bHi; vmcnt gate ----
    readAHi(buf);
    if (st_nxt) stageB_h(buf, kt + 2, 0);
    __builtin_amdgcn_s_barrier();
    asm volatile("s_waitcnt lgkmcnt(8)" ::: "memory");
    __builtin_amdgcn_s_setprio(1);
#pragma unroll
    for (int m = 0; m < 4; ++m)
#pragma unroll
      for (int n = 0; n < 2; ++n)
#pragma unroll
        for (int ks = 0; ks < 2; ++ks)
          acc[m][n + 2] = __builtin_amdgcn_mfma_i32_16x16x64_i8(aLo[m][ks], bHi[n][ks], acc[m][n + 2], 0, 0, 0);
    __builtin_amdgcn_s_setprio(0);
    if (st_nxt) {
      asm volatile("s_waitcnt vmcnt(2)" ::: "memory");   // tile kt+1 landed; P1's 2 fly
    } else {
      asm volatile("s_waitcnt vmcnt(0)" ::: "memory");
    }
    __builtin_amdgcn_s_barrier();

    // ---- P2: read aLo(kt+1); stage Ah0(kt+2)+Bh1(kt+2); MFMA Q10 = aHi x bLo ----
    if (rd_nxt) readALo(nxt);
    if (st_nxt) { stageA_h(buf, kt + 2, 0); stageB_h(buf, kt + 2, 1); }
    __builtin_amdgcn_s_barrier();
    if (rd_nxt) {
      asm volatile("s_waitcnt lgkmcnt(8)" ::: "memory");
    } else {
      asm volatile("s_waitcnt lgkmcnt(0)" ::: "memory");
    }
    __builtin_amdgcn_s_setprio(1);
#pragma unroll
    for (int m = 0; m < 4; ++m)
#pragma unroll
      for (int n = 0; n < 2; ++n)
#pragma unroll
        for (int ks = 0; ks < 2; ++ks)
          acc[m + 4][n] = __builtin_amdgcn_mfma_i32_16x16x64_i8(aHi[m][ks], bLo[n][ks], acc[m + 4][n], 0, 0, 0);
    __builtin_amdgcn_s_setprio(0);
    __builtin_amdgcn_s_barrier();

    // ---- P3: read bLo(kt+1); stage Ah1(kt+2); MFMA Q11 = aHi x bHi ----
    if (rd_nxt) readBLo(nxt);
    if (st_nxt) stageA_h(buf, kt + 2, 1);
    __builtin_amdgcn_s_barrier();
    if (rd_nxt) {
      asm volatile("s_waitcnt lgkmcnt(4)" ::: "memory");
    } else {
      asm volatile("s_waitcnt lgkmcnt(0)" ::: "memory");
    }
    __builtin_amdgcn_s_setprio(1);
#pragma unroll
    for (int m = 0; m < 4; ++m)
#pragma unroll
      for (int n = 0; n < 2; ++n)
#pragma unroll
        for (int ks = 0; ks < 2; ++ks)
          acc[m + 4][n + 2] = __builtin_amdgcn_mfma_i32_16x16x64_i8(aHi[m][ks], bHi[n][ks], acc[m + 4][n + 2], 0, 0, 0);
    __builtin_amdgcn_s_setprio(0);
    __builtin_amdgcn_s_barrier();
  }

  // epilogue: dequant + zero-point correction + bias
  const float cscale = p->cscale;
  int   cov[4];
  float bov[4];
#pragma unroll
  for (int n = 0; n < 4; ++n) {
    const int o_ = n0 + (wn << 6) + (n << 4) + lr;
    cov[n] = co[o_];
    bov[n] = bias[o_];
  }
#pragma unroll
  for (int m = 0; m < 8; ++m) {
    const int tbase = m0 + (wm << 7) + (m << 4) + (kg << 2);
    int ctv[4];
#pragma unroll
    for (int r = 0; r < 4; ++r) ctv[r] = ct[tbase + r];
#pragma unroll
    for (int n = 0; n < 4; ++n) {
      const int o_ = n0 + (wn << 6) + (n << 4) + lr;
#pragma unroll
      for (int r = 0; r < 4; ++r) {
        out[(size_t)(tbase + r) * O_DIM + o_] =
            (float)(acc[m][n][r] + cov[n] + ctv[r]) * cscale + bov[n];
      }
    }
  }
}

extern "C" void kernel_launch(void* const* d_in, const int* in_sizes, int n_in,
                              void* d_out, int out_size, void* d_ws, size_t ws_size,
                              hipStream_t stream) {
  const float* x      = (const float*)d_in[0];
  const float* w      = (const float*)d_in[1];
  const float* bias   = (const float*)d_in[2];
  const float* in_min = (const float*)d_in[3];
  const float* in_max = (const float*)d_in[4];
  float* out = (float*)d_out;

  uint8_t* ws = (uint8_t*)d_ws;
  unsigned* mm = (unsigned*)(ws + WS_MM);
  Params*   prm = (Params*)(ws + WS_PARAMS);
  int*      co = (int*)(ws + WS_CO);
  int*      s  = (int*)(ws + WS_S);
  int*      ct = (int*)(ws + WS_CT);
  int8_t*   qw = (int8_t*)(ws + WS_QW);
  int8_t*   qx = (int8_t*)(ws + WS_QX);

  float* dq_out   = out + (size_t)T_DIM * O_DIM;
  float* bias_out = dq_out + (size_t)O_DIM * K_DIM;

  init_kernel<<<1, 1, 0, stream>>>(mm);
  wminmax_kernel<<<512, 256, 0, stream>>>((const float4*)w, mm, O_DIM * K_DIM / 4);
  params_kernel<<<1, 1, 0, stream>>>(mm, in_min, in_max, prm);
  quantw_kernel<<<O_DIM, 256, 0, stream>>>(w, bias, prm, qw, co, dq_out, bias_out);
  quantx_kernel<<<N_FRAMES, 256, 0, stream>>>(x, prm, qx, s);
  ct_kernel<<<T_DIM / 256, 256, 0, stream>>>(s, prm, ct);
  gemm_kernel<<<(T_DIM / 256) * (O_DIM / 256), 512, 0, stream>>>(qx, qw, co, ct, bias, prm, out);
}